// Round 14
// baseline (211.941 us; speedup 1.0000x reference)
//
#include <hip/hip_runtime.h>
#include <math.h>

#define HID 128
#define HEADS 4
#define NEG_SLOPE 0.2f
#define LN_EPS 1e-5f
#define LOG2E 1.44269504088896f
#define BCAP 4096   // per-bucket capacity (avg 2046 for N=50K, E=800K)

typedef unsigned short ushortT;
typedef unsigned int uintT;
typedef __attribute__((ext_vector_type(8))) short bf16x8;
typedef __attribute__((ext_vector_type(4))) float f32x4;

__device__ __forceinline__ float lrelu(float v) { return v > 0.f ? v : NEG_SLOPE * v; }
__device__ __forceinline__ float bflo(uintT v) { return __uint_as_float(v << 16); }
__device__ __forceinline__ float bfhi(uintT v) { return __uint_as_float(v & 0xffff0000u); }

__device__ __forceinline__ ushortT f2bf(float f) {
    uintT u = __float_as_uint(f);
    u += 0x7fffu + ((u >> 16) & 1u);   // round-to-nearest-even
    return (ushortT)(u >> 16);
}

// ---------------- edge binning (pass A): bin edges by dst>>7; gcur ends as per-bucket counts ----------------
__global__ __launch_bounds__(256) void binA_k(const int* __restrict__ src, const int* __restrict__ dst,
                                              int* __restrict__ gcur, int2* __restrict__ buf, int E, int NB) {
    __shared__ int hist[512];
    __shared__ int bbase[512];
    __shared__ int lcur[512];
    int t = threadIdx.x;
    for (int i = t; i < NB; i += 256) { hist[i] = 0; lcur[i] = 0; }
    __syncthreads();
    int e0 = blockIdx.x * 4096;
    int2 ed[16];
    #pragma unroll
    for (int j = 0; j < 16; ++j) {
        int idx = e0 + j * 256 + t;
        if (idx < E) {
            ed[j].x = src[idx];
            ed[j].y = dst[idx];
            atomicAdd(&hist[ed[j].y >> 7], 1);
        } else {
            ed[j].y = -1;
        }
    }
    __syncthreads();
    for (int i = t; i < NB; i += 256) {
        int c = hist[i];
        bbase[i] = c > 0 ? atomicAdd(&gcur[i], c) : 0;
    }
    __syncthreads();
    #pragma unroll
    for (int j = 0; j < 16; ++j) {
        if (ed[j].y >= 0) {
            int b = ed[j].y >> 7;
            int pos = bbase[b] + atomicAdd(&lcur[b], 1);
            buf[(size_t)b * BCAP + pos] = ed[j];
        }
    }
}

// ---------------- pass B: compute own bucket base, per-node count+scan -> off, scatter csr (BYTE offsets: src*256) ----------------
__global__ __launch_bounds__(256) void binB_k(const int2* __restrict__ buf, const int* __restrict__ bcnt,
                                              int* __restrict__ off, int* __restrict__ csr, int Nn, int E) {
    __shared__ int cnt[128];
    __shared__ int pre[128];
    __shared__ int cur[128];
    __shared__ int sbase;
    int t = threadIdx.x, b = blockIdx.x;
    if (t == 0) sbase = 0;
    if (t < 128) cnt[t] = 0;
    __syncthreads();
    int bacc = 0;
    for (int i = t; i < b; i += 256) bacc += bcnt[i];
    #pragma unroll
    for (int m = 1; m < 64; m <<= 1) bacc += __shfl_xor(bacc, m, 64);
    if ((t & 63) == 0 && bacc != 0) atomicAdd(&sbase, bacc);
    int nb = bcnt[b];
    int nodebase = b << 7;
    for (int i = t; i < nb; i += 256)
        atomicAdd(&cnt[buf[(size_t)b * BCAP + i].y - nodebase], 1);
    __syncthreads();
    if (t < 128) pre[t] = cnt[t];
    __syncthreads();
    #pragma unroll
    for (int ofs = 1; ofs < 128; ofs <<= 1) {
        int v = 0;
        if (t < 128 && t >= ofs) v = pre[t - ofs];
        __syncthreads();
        if (t < 128) pre[t] += v;
        __syncthreads();
    }
    if (t < 128) {
        int node = nodebase + t;
        int o = sbase + pre[t] - cnt[t];
        if (node < Nn) off[node] = o;
        cur[t] = o;
    }
    if (b == 0 && t == 0) off[Nn] = E;
    __syncthreads();
    for (int i = t; i < nb; i += 256) {
        int2 e = buf[(size_t)b * BCAP + i];
        int p = atomicAdd(&cur[e.y - nodebase], 1);
        csr[p] = e.x << 8;     // byte offset into 256B-per-node tables
    }
}

// ---------------- weight conversion into MFMA B-fragment layout (+ zero gcur) ----------------
__global__ __launch_bounds__(256) void wconv4_k(const float* __restrict__ rw, const float* __restrict__ W1,
                                                const float* __restrict__ W2, const float* __restrict__ W3,
                                                ushortT* __restrict__ rwf, ushortT* __restrict__ W1f,
                                                ushortT* __restrict__ W2f, ushortT* __restrict__ W3f,
                                                int* __restrict__ gcur, int NB) {
    int id = blockIdx.x * 256 + threadIdx.x;
    if (id < NB) gcur[id] = 0;
    const float* Wsrc; ushortT* Wdst; int kdiv; int lid;
    if (id < 8192)        { Wsrc = rw; Wdst = rwf; kdiv = 2; lid = id; }
    else if (id < 16384)  { Wsrc = W1; Wdst = W1f; kdiv = 2; lid = id - 8192; }
    else if (id < 32768)  { Wsrc = W2; Wdst = W2f; kdiv = 4; lid = id - 16384; }
    else if (id < 49152)  { Wsrc = W3; Wdst = W3f; kdiv = 4; lid = id - 32768; }
    else return;
    int i = lid & 7;
    int lane = (lid >> 3) & 63;
    int rest = lid >> 9;            // j*kdiv + ks
    int ks = rest % kdiv;
    int j = rest / kdiv;
    int k = ks * 32 + (lane >> 4) * 8 + i;
    int n = j * 16 + (lane & 15);
    Wdst[lid] = f2bf(Wsrc[k * HID + n]);
}

// ---------------- MFMA GEMM (x layer, K=64): inline fp32->bf16 A, bf16 residual + xl + attn dots (x log2e) ----------------
__global__ __launch_bounds__(256) void gemm_mfma_x(
        const float* __restrict__ X, const ushortT* __restrict__ rwf, const ushortT* __restrict__ W1f,
        const float* __restrict__ rb, const float* __restrict__ a_srcp, const float* __restrict__ a_dstp,
        ushortT* __restrict__ Resh, ushortT* __restrict__ Ch,
        float* __restrict__ als, float* __restrict__ ald, int M) {
    int t = threadIdx.x;
    int wave = t >> 6, lane = t & 63;
    int row0 = blockIdx.x * 64 + wave * 16;
    int cl = lane & 15, grp = lane >> 4;
    int rA = row0 + cl;
    f32x4 accR[8] = {};
    f32x4 acc1[8] = {};
    #pragma unroll
    for (int ks = 0; ks < 2; ++ks) {
        bf16x8 afr = {};
        if (rA < M) {
            const float* xr = &X[(size_t)rA * 64 + ks * 32 + grp * 8];
            float4 a0 = *(const float4*)xr;
            float4 a1 = *(const float4*)(xr + 4);
            afr[0] = (short)f2bf(a0.x); afr[1] = (short)f2bf(a0.y);
            afr[2] = (short)f2bf(a0.z); afr[3] = (short)f2bf(a0.w);
            afr[4] = (short)f2bf(a1.x); afr[5] = (short)f2bf(a1.y);
            afr[6] = (short)f2bf(a1.z); afr[7] = (short)f2bf(a1.w);
        }
        #pragma unroll
        for (int j = 0; j < 8; ++j) {
            bf16x8 br = *(const bf16x8*)&rwf[(((size_t)j * 2 + ks) * 64 + lane) * 8];
            accR[j] = __builtin_amdgcn_mfma_f32_16x16x32_bf16(afr, br, accR[j], 0, 0, 0);
            bf16x8 b1 = *(const bf16x8*)&W1f[(((size_t)j * 2 + ks) * 64 + lane) * 8];
            acc1[j] = __builtin_amdgcn_mfma_f32_16x16x32_bf16(afr, b1, acc1[j], 0, 0, 0);
        }
    }
    float asv[8], adv[8], rbv[8];
    #pragma unroll
    for (int j = 0; j < 8; ++j) {
        asv[j] = a_srcp[j * 16 + cl] * LOG2E;
        adv[j] = a_dstp[j * 16 + cl] * LOG2E;
        rbv[j] = rb[j * 16 + cl];
    }
    #pragma unroll
    for (int reg = 0; reg < 4; ++reg) {
        int r = row0 + grp * 4 + reg;
        bool ok = r < M;
        if (ok) {
            #pragma unroll
            for (int j = 0; j < 8; ++j) {
                Resh[(size_t)r * HID + j * 16 + cl] = f2bf(accR[j][reg] + rbv[j]);
                Ch[(size_t)r * HID + j * 16 + cl] = f2bf(acc1[j][reg]);
            }
        }
        float ps[4], pd[4];
        #pragma unroll
        for (int h = 0; h < 4; ++h) {
            ps[h] = acc1[2 * h][reg] * asv[2 * h] + acc1[2 * h + 1][reg] * asv[2 * h + 1];
            pd[h] = acc1[2 * h][reg] * adv[2 * h] + acc1[2 * h + 1][reg] * adv[2 * h + 1];
        }
        #pragma unroll
        for (int m = 1; m < 16; m <<= 1) {
            #pragma unroll
            for (int h = 0; h < 4; ++h) {
                ps[h] += __shfl_xor(ps[h], m, 64);
                pd[h] += __shfl_xor(pd[h], m, 64);
            }
        }
        if (cl == 0 && ok) {
            *(float4*)&als[(size_t)r * 4] = make_float4(ps[0], ps[1], ps[2], ps[3]);
            *(float4*)&ald[(size_t)r * 4] = make_float4(pd[0], pd[1], pd[2], pd[3]);
        }
    }
}

// ---------------- MFMA GEMM (hidden layers, K=128): Ch + attn dots (x log2e) ----------------
__global__ __launch_bounds__(256) void gemm_mfma_h(
        const ushortT* __restrict__ Ah, const ushortT* __restrict__ Wf,
        const float* __restrict__ a_srcp, const float* __restrict__ a_dstp,
        ushortT* __restrict__ Ch, float* __restrict__ als, float* __restrict__ ald, int M) {
    int t = threadIdx.x;
    int wave = t >> 6, lane = t & 63;
    int row0 = blockIdx.x * 64 + wave * 16;
    int cl = lane & 15, grp = lane >> 4;
    int rA = row0 + cl;
    f32x4 acc[8] = {};
    #pragma unroll
    for (int ks = 0; ks < 4; ++ks) {
        bf16x8 afr = {};
        if (rA < M) afr = *(const bf16x8*)&Ah[(size_t)rA * HID + ks * 32 + grp * 8];
        #pragma unroll
        for (int j = 0; j < 8; ++j) {
            bf16x8 br = *(const bf16x8*)&Wf[(((size_t)j * 4 + ks) * 64 + lane) * 8];
            acc[j] = __builtin_amdgcn_mfma_f32_16x16x32_bf16(afr, br, acc[j], 0, 0, 0);
        }
    }
    float asv[8], adv[8];
    #pragma unroll
    for (int j = 0; j < 8; ++j) {
        asv[j] = a_srcp[j * 16 + cl] * LOG2E;
        adv[j] = a_dstp[j * 16 + cl] * LOG2E;
    }
    #pragma unroll
    for (int reg = 0; reg < 4; ++reg) {
        int r = row0 + grp * 4 + reg;
        bool ok = r < M;
        if (ok) {
            #pragma unroll
            for (int j = 0; j < 8; ++j)
                Ch[(size_t)r * HID + j * 16 + cl] = f2bf(acc[j][reg]);
        }
        float ps[4], pd[4];
        #pragma unroll
        for (int h = 0; h < 4; ++h) {
            ps[h] = acc[2 * h][reg] * asv[2 * h] + acc[2 * h + 1][reg] * asv[2 * h + 1];
            pd[h] = acc[2 * h][reg] * adv[2 * h] + acc[2 * h + 1][reg] * adv[2 * h + 1];
        }
        #pragma unroll
        for (int m = 1; m < 16; m <<= 1) {
            #pragma unroll
            for (int h = 0; h < 4; ++h) {
                ps[h] += __shfl_xor(ps[h], m, 64);
                pd[h] += __shfl_xor(pd[h], m, 64);
            }
        }
        if (cl == 0 && ok) {
            *(float4*)&als[(size_t)r * 4] = make_float4(ps[0], ps[1], ps[2], ps[3]);
            *(float4*)&ald[(size_t)r * 4] = make_float4(pd[0], pd[1], pd[2], pd[3]);
        }
    }
}

// ---------------- fully fused GAT: single-pass online softmax (exp2) + LN + ReLU + bf16 residual ----------------
// csr holds BYTE offsets (src*256): all gather loads are SGPR-base + 32-bit voffset (no 64-bit addr math).
// 2-edge unrolled + csr/als software pipelining.
__global__ __launch_bounds__(256) void gat_fused(
        const ushortT* __restrict__ xlh, const float* __restrict__ als,
        const float* __restrict__ ald, const int* __restrict__ off,
        const int* __restrict__ csr, const float* __restrict__ bias,
        const float* __restrict__ g, const float* __restrict__ be,
        ushortT* __restrict__ resio,
        const float* __restrict__ Wo, const float* __restrict__ aso, const float* __restrict__ ado,
        float4* __restrict__ xpack, int Nn) {
    int gid = blockIdx.x * 256 + threadIdx.x;
    int wid = gid >> 6, lane = threadIdx.x & 63;
    if (wid >= Nn) return;
    int q = lane >> 4;
    int cl = lane & 15;
    int h = cl >> 2;
    const char* xb = (const char*)xlh;
    const char* ab = (const char*)als;
    uintT cl16 = (uintT)cl * 16;   // byte offset of this lane's uint4 within a row
    uintT h4 = (uintT)h * 4;       // byte offset of this lane's head within als row
    float aldh = ald[wid * 4 + h];
    float eh = lrelu(als[wid * 4 + h] + aldh);   // self logit (log2-scaled) = softmax shift
    int b = off[wid], e = off[wid + 1];
    float acc[8] = {};
    float dsum = 0.f;
    int c = b + q;
    // pipeline prologue
    int v0n = 0, v1n = 0;
    if (c < e) v0n = csr[c];
    if (c + 4 < e) v1n = csr[c + 4];
    float al0n = *(const float*)(ab + (((uintT)v0n >> 4) + h4));
    float al1n = *(const float*)(ab + (((uintT)v1n >> 4) + h4));
    for (; c + 4 < e; c += 8) {
        int v0 = v0n, v1 = v1n;
        float al0 = al0n, al1 = al1n;
        uint4 hv0 = *(const uint4*)(xb + ((uintT)v0 + cl16));
        uint4 hv1 = *(const uint4*)(xb + ((uintT)v1 + cl16));
        if (c + 8 < e) v0n = csr[c + 8];
        if (c + 12 < e) v1n = csr[c + 12];
        al0n = *(const float*)(ab + (((uintT)v0n >> 4) + h4));
        al1n = *(const float*)(ab + (((uintT)v1n >> 4) + h4));
        float w0 = exp2f(lrelu(al0 + aldh) - eh);
        float w1 = exp2f(lrelu(al1 + aldh) - eh);
        dsum += w0 + w1;
        acc[0] = fmaf(w0, bflo(hv0.x), acc[0]);
        acc[1] = fmaf(w0, bfhi(hv0.x), acc[1]);
        acc[2] = fmaf(w0, bflo(hv0.y), acc[2]);
        acc[3] = fmaf(w0, bfhi(hv0.y), acc[3]);
        acc[4] = fmaf(w0, bflo(hv0.z), acc[4]);
        acc[5] = fmaf(w0, bfhi(hv0.z), acc[5]);
        acc[6] = fmaf(w0, bflo(hv0.w), acc[6]);
        acc[7] = fmaf(w0, bfhi(hv0.w), acc[7]);
        acc[0] = fmaf(w1, bflo(hv1.x), acc[0]);
        acc[1] = fmaf(w1, bfhi(hv1.x), acc[1]);
        acc[2] = fmaf(w1, bflo(hv1.y), acc[2]);
        acc[3] = fmaf(w1, bfhi(hv1.y), acc[3]);
        acc[4] = fmaf(w1, bflo(hv1.z), acc[4]);
        acc[5] = fmaf(w1, bfhi(hv1.z), acc[5]);
        acc[6] = fmaf(w1, bflo(hv1.w), acc[6]);
        acc[7] = fmaf(w1, bfhi(hv1.w), acc[7]);
    }
    if (c < e) {
        // pipeline invariant: v0n == csr[c], al0n == its als value
        uint4 hv = *(const uint4*)(xb + ((uintT)v0n + cl16));
        float w = exp2f(lrelu(al0n + aldh) - eh);
        dsum += w;
        acc[0] = fmaf(w, bflo(hv.x), acc[0]);
        acc[1] = fmaf(w, bfhi(hv.x), acc[1]);
        acc[2] = fmaf(w, bflo(hv.y), acc[2]);
        acc[3] = fmaf(w, bfhi(hv.y), acc[3]);
        acc[4] = fmaf(w, bflo(hv.z), acc[4]);
        acc[5] = fmaf(w, bfhi(hv.z), acc[5]);
        acc[6] = fmaf(w, bflo(hv.w), acc[6]);
        acc[7] = fmaf(w, bfhi(hv.w), acc[7]);
    }
    #pragma unroll
    for (int k = 0; k < 8; ++k) {
        acc[k] += __shfl_xor(acc[k], 16, 64);
        acc[k] += __shfl_xor(acc[k], 32, 64);
    }
    dsum += __shfl_xor(dsum, 16, 64);
    dsum += __shfl_xor(dsum, 32, 64);
    float inv = 1.f / (dsum + 1.f + 1e-16f);     // self weight = exp2(0) = 1
    uint4 sv = *(const uint4*)&xlh[(size_t)wid * HID + cl * 8];
    float sx[8];
    sx[0] = bflo(sv.x); sx[1] = bfhi(sv.x);
    sx[2] = bflo(sv.y); sx[3] = bfhi(sv.y);
    sx[4] = bflo(sv.z); sx[5] = bfhi(sv.z);
    sx[6] = bflo(sv.w); sx[7] = bfhi(sv.w);
    float4 bi0 = *(const float4*)&bias[cl * 8];
    float4 bi1 = *(const float4*)&bias[cl * 8 + 4];
    float o[8];
    #pragma unroll
    for (int k = 0; k < 8; ++k) {
        float bb = k < 4 ? (&bi0.x)[k] : (&bi1.x)[k - 4];
        o[k] = fmaf(acc[k] + sx[k], inv, bb);
    }
    float s1 = o[0] + o[1] + o[2] + o[3] + o[4] + o[5] + o[6] + o[7];
    #pragma unroll
    for (int m = 1; m < 16; m <<= 1) s1 += __shfl_xor(s1, m, 64);
    float mu = s1 * (1.0f / HID);
    float qv = 0.f;
    #pragma unroll
    for (int k = 0; k < 8; ++k) { float d = o[k] - mu; qv += d * d; }
    #pragma unroll
    for (int m = 1; m < 16; m <<= 1) qv += __shfl_xor(qv, m, 64);
    float rs = rsqrtf(qv * (1.0f / HID) + LN_EPS);
    if (q == 0) {
        float4 g0 = *(const float4*)&g[cl * 8];
        float4 g1 = *(const float4*)&g[cl * 8 + 4];
        float4 be0 = *(const float4*)&be[cl * 8];
        float4 be1 = *(const float4*)&be[cl * 8 + 4];
        uint4 rv = *(const uint4*)&resio[(size_t)wid * HID + cl * 8];
        float rr[8];
        rr[0] = bflo(rv.x); rr[1] = bfhi(rv.x);
        rr[2] = bflo(rv.y); rr[3] = bfhi(rv.y);
        rr[4] = bflo(rv.z); rr[5] = bfhi(rv.z);
        rr[6] = bflo(rv.w); rr[7] = bfhi(rv.w);
        float w[8];
        #pragma unroll
        for (int k = 0; k < 8; ++k) {
            float gg = k < 4 ? (&g0.x)[k] : (&g1.x)[k - 4];
            float ee = k < 4 ? (&be0.x)[k] : (&be1.x)[k - 4];
            w[k] = fmaxf((o[k] - mu) * rs * gg + ee, 0.f) + rr[k];
        }
        if (Wo) {
            float p0 = 0.f, p1 = 0.f;
            #pragma unroll
            for (int k = 0; k < 8; ++k) {
                int ch = cl * 8 + k;
                p0 = fmaf(w[k], Wo[ch * 2 + 0], p0);
                p1 = fmaf(w[k], Wo[ch * 2 + 1], p1);
            }
            #pragma unroll
            for (int m = 1; m < 16; m <<= 1) {
                p0 += __shfl_xor(p0, m, 64);
                p1 += __shfl_xor(p1, m, 64);
            }
            if (cl == 0) {
                float a_s = (p0 * aso[0] + p1 * aso[1]) * LOG2E;
                float a_d = (p0 * ado[0] + p1 * ado[1]) * LOG2E;
                xpack[wid] = make_float4(p0, p1, a_s, a_d);
            }
        } else {
            ushort4 hv0, hv1;
            hv0.x = f2bf(w[0]); hv0.y = f2bf(w[1]); hv0.z = f2bf(w[2]); hv0.w = f2bf(w[3]);
            hv1.x = f2bf(w[4]); hv1.y = f2bf(w[5]); hv1.z = f2bf(w[6]); hv1.w = f2bf(w[7]);
            *(ushort4*)&resio[(size_t)wid * HID + cl * 8] = hv0;
            *(ushort4*)&resio[(size_t)wid * HID + cl * 8 + 4] = hv1;
        }
    }
}

// ---------------- output aggregation: 16 lanes/node, 4 nodes/wave (csr = byte offsets) ----------------
__global__ __launch_bounds__(256) void out_agg(const float4* __restrict__ xpack, const int* __restrict__ off,
                                               const int* __restrict__ csr, const float* __restrict__ bo,
                                               float* __restrict__ out, int Nn) {
    int gid = blockIdx.x * 256 + threadIdx.x;
    int wid = gid >> 4;
    int l = threadIdx.x & 15;
    if (wid >= Nn) return;
    const char* pb = (const char*)xpack;
    float4 self = xpack[wid];
    float aldn = self.w;
    float eself = lrelu(self.z + aldn);
    int b = off[wid], e = off[wid + 1];
    float dl = 0.f, a0 = 0.f, a1 = 0.f;
    for (int j = b + l; j < e; j += 16) {
        float4 v = *(const float4*)(pb + ((uintT)csr[j] >> 4));
        float w = exp2f(lrelu(v.z + aldn) - eself);
        dl += w;
        a0 += w * v.x;
        a1 += w * v.y;
    }
    #pragma unroll
    for (int m = 1; m < 16; m <<= 1) {
        dl += __shfl_xor(dl, m, 64);
        a0 += __shfl_xor(a0, m, 64);
        a1 += __shfl_xor(a1, m, 64);
    }
    if (l == 0) {
        dl += 1.f;   // self weight exp2(0)
        a0 += self.x;
        a1 += self.y;
        float inv = 1.f / (dl + 1e-16f);
        out[wid * 2 + 0] = a0 * inv + bo[0];
        out[wid * 2 + 1] = a1 * inv + bo[1];
    }
}

extern "C" void kernel_launch(void* const* d_in, const int* in_sizes, int n_in,
                              void* d_out, int out_size, void* d_ws, size_t ws_size,
                              hipStream_t stream) {
    const float* x   = (const float*)d_in[0];
    const int*   ei  = (const int*)d_in[1];
    const float* W1  = (const float*)d_in[2];
    const float* as1 = (const float*)d_in[3];
    const float* ad1 = (const float*)d_in[4];
    const float* b1  = (const float*)d_in[5];
    const float* g1  = (const float*)d_in[6];
    const float* be1 = (const float*)d_in[7];
    const float* rw  = (const float*)d_in[8];
    const float* rb  = (const float*)d_in[9];
    const float* W2  = (const float*)d_in[10];
    const float* as2 = (const float*)d_in[11];
    const float* ad2 = (const float*)d_in[12];
    const float* b2  = (const float*)d_in[13];
    const float* g2  = (const float*)d_in[14];
    const float* be2 = (const float*)d_in[15];
    const float* W3  = (const float*)d_in[16];
    const float* as3 = (const float*)d_in[17];
    const float* ad3 = (const float*)d_in[18];
    const float* b3  = (const float*)d_in[19];
    const float* g3  = (const float*)d_in[20];
    const float* be3 = (const float*)d_in[21];
    const float* Wo  = (const float*)d_in[22];
    const float* aso = (const float*)d_in[23];
    const float* ado = (const float*)d_in[24];
    const float* bo  = (const float*)d_in[25];

    int N = in_sizes[0] / 64;   // 50000
    int E = in_sizes[1] / 2;    // 800000
    const int* srcE = ei;
    const int* dstE = ei + E;
    int NB = (N + 127) >> 7;    // 391 buckets

    char* w = (char*)d_ws;
    auto alloc = [&](size_t b) { char* p = w; w += (b + 255) & ~(size_t)255; return p; };
    int* off    = (int*)alloc((size_t)(N + 1) * 4);
    int* gcur   = (int*)alloc((size_t)NB * 4);
    int* csr    = (int*)alloc((size_t)E * 4);
    int2* bbuf  = (int2*)alloc((size_t)NB * BCAP * 8);
    ushortT* hresh = (ushortT*)alloc((size_t)N * HID * 2);
    ushortT* xlh = (ushortT*)alloc((size_t)N * HID * 2);
    ushortT* rwf = (ushortT*)alloc(8192 * 2);
    ushortT* W1f = (ushortT*)alloc(8192 * 2);
    ushortT* W2f = (ushortT*)alloc(16384 * 2);
    ushortT* W3f = (ushortT*)alloc(16384 * 2);
    float* als  = (float*)alloc((size_t)N * HEADS * 4);
    float* ald  = (float*)alloc((size_t)N * HEADS * 4);
    float4* xpack = (float4*)alloc((size_t)N * 16);

    // weight conversion (+ zeroes gcur for binA)
    wconv4_k<<<192, 256, 0, stream>>>(rw, W1, W2, W3, rwf, W1f, W2f, W3f, gcur, NB);
    binA_k<<<(E + 4095) / 4096, 256, 0, stream>>>(srcE, dstE, gcur, bbuf, E, NB);
    binB_k<<<NB, 256, 0, stream>>>(bbuf, gcur, off, csr, N, E);

    int gG = (N + 63) / 64;   // MFMA gemm grid
    int gW = (N + 3) / 4;     // wave-per-node grid
    int gO = (N * 16 + 255) / 256;   // 16 lanes/node grid

    // ---- layer 1 (fused residual + W1 projection, MFMA, inline x->bf16) ----
    gemm_mfma_x<<<gG, 256, 0, stream>>>(x, rwf, W1f, rb, as1, ad1, hresh, xlh, als, ald, N);
    gat_fused<<<gW, 256, 0, stream>>>(xlh, als, ald, off, csr, b1, g1, be1, hresh,
                                      nullptr, nullptr, nullptr, nullptr, N);

    // ---- layer 2 ----
    gemm_mfma_h<<<gG, 256, 0, stream>>>(hresh, W2f, as2, ad2, xlh, als, ald, N);
    gat_fused<<<gW, 256, 0, stream>>>(xlh, als, ald, off, csr, b2, g2, be2, hresh,
                                      nullptr, nullptr, nullptr, nullptr, N);

    // ---- layer 3 (fused output projection) ----
    gemm_mfma_h<<<gG, 256, 0, stream>>>(hresh, W3f, as3, ad3, xlh, als, ald, N);
    gat_fused<<<gW, 256, 0, stream>>>(xlh, als, ald, off, csr, b3, g3, be3, hresh,
                                      Wo, aso, ado, xpack, N);

    // ---- output aggregation ----
    out_agg<<<gO, 256, 0, stream>>>(xpack, off, csr, bo, (float*)d_out, N);
}

// Round 15
// 211.836 us; speedup vs baseline: 1.0005x; 1.0005x over previous
//
#include <hip/hip_runtime.h>
#include <math.h>

#define HID 128
#define HEADS 4
#define NEG_SLOPE 0.2f
#define LN_EPS 1e-5f
#define LOG2E 1.44269504088896f
#define BCAP 4096   // per-bucket capacity (avg 2046 for N=50K, E=800K)

typedef unsigned short ushortT;
typedef unsigned int uintT;
typedef __attribute__((ext_vector_type(8))) short bf16x8;
typedef __attribute__((ext_vector_type(4))) float f32x4;
typedef __attribute__((ext_vector_type(2))) float f32x2;

__device__ __forceinline__ float lrelu(float v) { return v > 0.f ? v : NEG_SLOPE * v; }
__device__ __forceinline__ float bflo(uintT v) { return __uint_as_float(v << 16); }
__device__ __forceinline__ float bfhi(uintT v) { return __uint_as_float(v & 0xffff0000u); }

__device__ __forceinline__ ushortT f2bf(float f) {
    uintT u = __float_as_uint(f);
    u += 0x7fffu + ((u >> 16) & 1u);   // round-to-nearest-even
    return (ushortT)(u >> 16);
}

// ---------------- edge binning (pass A): bin edges by dst>>7; gcur ends as per-bucket counts ----------------
__global__ __launch_bounds__(256) void binA_k(const int* __restrict__ src, const int* __restrict__ dst,
                                              int* __restrict__ gcur, int2* __restrict__ buf, int E, int NB) {
    __shared__ int hist[512];
    __shared__ int bbase[512];
    __shared__ int lcur[512];
    int t = threadIdx.x;
    for (int i = t; i < NB; i += 256) { hist[i] = 0; lcur[i] = 0; }
    __syncthreads();
    int e0 = blockIdx.x * 4096;
    int2 ed[16];
    #pragma unroll
    for (int j = 0; j < 16; ++j) {
        int idx = e0 + j * 256 + t;
        if (idx < E) {
            ed[j].x = src[idx];
            ed[j].y = dst[idx];
            atomicAdd(&hist[ed[j].y >> 7], 1);
        } else {
            ed[j].y = -1;
        }
    }
    __syncthreads();
    for (int i = t; i < NB; i += 256) {
        int c = hist[i];
        bbase[i] = c > 0 ? atomicAdd(&gcur[i], c) : 0;
    }
    __syncthreads();
    #pragma unroll
    for (int j = 0; j < 16; ++j) {
        if (ed[j].y >= 0) {
            int b = ed[j].y >> 7;
            int pos = bbase[b] + atomicAdd(&lcur[b], 1);
            buf[(size_t)b * BCAP + pos] = ed[j];
        }
    }
}

// ---------------- pass B: compute own bucket base, per-node count+scan -> off, scatter csr (BYTE offsets: src*256) ----------------
__global__ __launch_bounds__(256) void binB_k(const int2* __restrict__ buf, const int* __restrict__ bcnt,
                                              int* __restrict__ off, int* __restrict__ csr, int Nn, int E) {
    __shared__ int cnt[128];
    __shared__ int pre[128];
    __shared__ int cur[128];
    __shared__ int sbase;
    int t = threadIdx.x, b = blockIdx.x;
    if (t == 0) sbase = 0;
    if (t < 128) cnt[t] = 0;
    __syncthreads();
    int bacc = 0;
    for (int i = t; i < b; i += 256) bacc += bcnt[i];
    #pragma unroll
    for (int m = 1; m < 64; m <<= 1) bacc += __shfl_xor(bacc, m, 64);
    if ((t & 63) == 0 && bacc != 0) atomicAdd(&sbase, bacc);
    int nb = bcnt[b];
    int nodebase = b << 7;
    for (int i = t; i < nb; i += 256)
        atomicAdd(&cnt[buf[(size_t)b * BCAP + i].y - nodebase], 1);
    __syncthreads();
    if (t < 128) pre[t] = cnt[t];
    __syncthreads();
    #pragma unroll
    for (int ofs = 1; ofs < 128; ofs <<= 1) {
        int v = 0;
        if (t < 128 && t >= ofs) v = pre[t - ofs];
        __syncthreads();
        if (t < 128) pre[t] += v;
        __syncthreads();
    }
    if (t < 128) {
        int node = nodebase + t;
        int o = sbase + pre[t] - cnt[t];
        if (node < Nn) off[node] = o;
        cur[t] = o;
    }
    if (b == 0 && t == 0) off[Nn] = E;
    __syncthreads();
    for (int i = t; i < nb; i += 256) {
        int2 e = buf[(size_t)b * BCAP + i];
        int p = atomicAdd(&cur[e.y - nodebase], 1);
        csr[p] = e.x << 8;     // byte offset into 256B-per-node tables
    }
}

// ---------------- weight conversion into MFMA B-fragment layout (+ zero gcur) ----------------
__global__ __launch_bounds__(256) void wconv4_k(const float* __restrict__ rw, const float* __restrict__ W1,
                                                const float* __restrict__ W2, const float* __restrict__ W3,
                                                ushortT* __restrict__ rwf, ushortT* __restrict__ W1f,
                                                ushortT* __restrict__ W2f, ushortT* __restrict__ W3f,
                                                int* __restrict__ gcur, int NB) {
    int id = blockIdx.x * 256 + threadIdx.x;
    if (id < NB) gcur[id] = 0;
    const float* Wsrc; ushortT* Wdst; int kdiv; int lid;
    if (id < 8192)        { Wsrc = rw; Wdst = rwf; kdiv = 2; lid = id; }
    else if (id < 16384)  { Wsrc = W1; Wdst = W1f; kdiv = 2; lid = id - 8192; }
    else if (id < 32768)  { Wsrc = W2; Wdst = W2f; kdiv = 4; lid = id - 16384; }
    else if (id < 49152)  { Wsrc = W3; Wdst = W3f; kdiv = 4; lid = id - 32768; }
    else return;
    int i = lid & 7;
    int lane = (lid >> 3) & 63;
    int rest = lid >> 9;            // j*kdiv + ks
    int ks = rest % kdiv;
    int j = rest / kdiv;
    int k = ks * 32 + (lane >> 4) * 8 + i;
    int n = j * 16 + (lane & 15);
    Wdst[lid] = f2bf(Wsrc[k * HID + n]);
}

// ---------------- MFMA GEMM (x layer, K=64): inline fp32->bf16 A, bf16 residual + xl + attn dots (x log2e) ----------------
__global__ __launch_bounds__(256) void gemm_mfma_x(
        const float* __restrict__ X, const ushortT* __restrict__ rwf, const ushortT* __restrict__ W1f,
        const float* __restrict__ rb, const float* __restrict__ a_srcp, const float* __restrict__ a_dstp,
        ushortT* __restrict__ Resh, ushortT* __restrict__ Ch,
        float* __restrict__ als, float* __restrict__ ald, int M) {
    int t = threadIdx.x;
    int wave = t >> 6, lane = t & 63;
    int row0 = blockIdx.x * 64 + wave * 16;
    int cl = lane & 15, grp = lane >> 4;
    int rA = row0 + cl;
    f32x4 accR[8] = {};
    f32x4 acc1[8] = {};
    #pragma unroll
    for (int ks = 0; ks < 2; ++ks) {
        bf16x8 afr = {};
        if (rA < M) {
            const float* xr = &X[(size_t)rA * 64 + ks * 32 + grp * 8];
            float4 a0 = *(const float4*)xr;
            float4 a1 = *(const float4*)(xr + 4);
            afr[0] = (short)f2bf(a0.x); afr[1] = (short)f2bf(a0.y);
            afr[2] = (short)f2bf(a0.z); afr[3] = (short)f2bf(a0.w);
            afr[4] = (short)f2bf(a1.x); afr[5] = (short)f2bf(a1.y);
            afr[6] = (short)f2bf(a1.z); afr[7] = (short)f2bf(a1.w);
        }
        #pragma unroll
        for (int j = 0; j < 8; ++j) {
            bf16x8 br = *(const bf16x8*)&rwf[(((size_t)j * 2 + ks) * 64 + lane) * 8];
            accR[j] = __builtin_amdgcn_mfma_f32_16x16x32_bf16(afr, br, accR[j], 0, 0, 0);
            bf16x8 b1 = *(const bf16x8*)&W1f[(((size_t)j * 2 + ks) * 64 + lane) * 8];
            acc1[j] = __builtin_amdgcn_mfma_f32_16x16x32_bf16(afr, b1, acc1[j], 0, 0, 0);
        }
    }
    float asv[8], adv[8], rbv[8];
    #pragma unroll
    for (int j = 0; j < 8; ++j) {
        asv[j] = a_srcp[j * 16 + cl] * LOG2E;
        adv[j] = a_dstp[j * 16 + cl] * LOG2E;
        rbv[j] = rb[j * 16 + cl];
    }
    #pragma unroll
    for (int reg = 0; reg < 4; ++reg) {
        int r = row0 + grp * 4 + reg;
        bool ok = r < M;
        if (ok) {
            #pragma unroll
            for (int j = 0; j < 8; ++j) {
                Resh[(size_t)r * HID + j * 16 + cl] = f2bf(accR[j][reg] + rbv[j]);
                Ch[(size_t)r * HID + j * 16 + cl] = f2bf(acc1[j][reg]);
            }
        }
        float ps[4], pd[4];
        #pragma unroll
        for (int h = 0; h < 4; ++h) {
            ps[h] = acc1[2 * h][reg] * asv[2 * h] + acc1[2 * h + 1][reg] * asv[2 * h + 1];
            pd[h] = acc1[2 * h][reg] * adv[2 * h] + acc1[2 * h + 1][reg] * adv[2 * h + 1];
        }
        #pragma unroll
        for (int m = 1; m < 16; m <<= 1) {
            #pragma unroll
            for (int h = 0; h < 4; ++h) {
                ps[h] += __shfl_xor(ps[h], m, 64);
                pd[h] += __shfl_xor(pd[h], m, 64);
            }
        }
        if (cl == 0 && ok) {
            *(float4*)&als[(size_t)r * 4] = make_float4(ps[0], ps[1], ps[2], ps[3]);
            *(float4*)&ald[(size_t)r * 4] = make_float4(pd[0], pd[1], pd[2], pd[3]);
        }
    }
}

// ---------------- MFMA GEMM (hidden layers, K=128): Ch + attn dots (x log2e) ----------------
__global__ __launch_bounds__(256) void gemm_mfma_h(
        const ushortT* __restrict__ Ah, const ushortT* __restrict__ Wf,
        const float* __restrict__ a_srcp, const float* __restrict__ a_dstp,
        ushortT* __restrict__ Ch, float* __restrict__ als, float* __restrict__ ald, int M) {
    int t = threadIdx.x;
    int wave = t >> 6, lane = t & 63;
    int row0 = blockIdx.x * 64 + wave * 16;
    int cl = lane & 15, grp = lane >> 4;
    int rA = row0 + cl;
    f32x4 acc[8] = {};
    #pragma unroll
    for (int ks = 0; ks < 4; ++ks) {
        bf16x8 afr = {};
        if (rA < M) afr = *(const bf16x8*)&Ah[(size_t)rA * HID + ks * 32 + grp * 8];
        #pragma unroll
        for (int j = 0; j < 8; ++j) {
            bf16x8 br = *(const bf16x8*)&Wf[(((size_t)j * 4 + ks) * 64 + lane) * 8];
            acc[j] = __builtin_amdgcn_mfma_f32_16x16x32_bf16(afr, br, acc[j], 0, 0, 0);
        }
    }
    float asv[8], adv[8];
    #pragma unroll
    for (int j = 0; j < 8; ++j) {
        asv[j] = a_srcp[j * 16 + cl] * LOG2E;
        adv[j] = a_dstp[j * 16 + cl] * LOG2E;
    }
    #pragma unroll
    for (int reg = 0; reg < 4; ++reg) {
        int r = row0 + grp * 4 + reg;
        bool ok = r < M;
        if (ok) {
            #pragma unroll
            for (int j = 0; j < 8; ++j)
                Ch[(size_t)r * HID + j * 16 + cl] = f2bf(acc[j][reg]);
        }
        float ps[4], pd[4];
        #pragma unroll
        for (int h = 0; h < 4; ++h) {
            ps[h] = acc[2 * h][reg] * asv[2 * h] + acc[2 * h + 1][reg] * asv[2 * h + 1];
            pd[h] = acc[2 * h][reg] * adv[2 * h] + acc[2 * h + 1][reg] * adv[2 * h + 1];
        }
        #pragma unroll
        for (int m = 1; m < 16; m <<= 1) {
            #pragma unroll
            for (int h = 0; h < 4; ++h) {
                ps[h] += __shfl_xor(ps[h], m, 64);
                pd[h] += __shfl_xor(pd[h], m, 64);
            }
        }
        if (cl == 0 && ok) {
            *(float4*)&als[(size_t)r * 4] = make_float4(ps[0], ps[1], ps[2], ps[3]);
            *(float4*)&ald[(size_t)r * 4] = make_float4(pd[0], pd[1], pd[2], pd[3]);
        }
    }
}

// ---------------- fully fused GAT: single-pass online softmax (exp2) + LN + ReLU + bf16 residual ----------------
// Packed-f32 accumulation (v_pk_fma_f32 via __builtin_elementwise_fma on float2): halves the FMA issue count.
// csr holds BYTE offsets; 2-edge unrolled + csr/als software pipelining.
__global__ __launch_bounds__(256) void gat_fused(
        const ushortT* __restrict__ xlh, const float* __restrict__ als,
        const float* __restrict__ ald, const int* __restrict__ off,
        const int* __restrict__ csr, const float* __restrict__ bias,
        const float* __restrict__ g, const float* __restrict__ be,
        ushortT* __restrict__ resio,
        const float* __restrict__ Wo, const float* __restrict__ aso, const float* __restrict__ ado,
        float4* __restrict__ xpack, int Nn) {
    int gid = blockIdx.x * 256 + threadIdx.x;
    int wid = gid >> 6, lane = threadIdx.x & 63;
    if (wid >= Nn) return;
    int q = lane >> 4;
    int cl = lane & 15;
    int h = cl >> 2;
    const char* xb = (const char*)xlh;
    const char* ab = (const char*)als;
    uintT cl16 = (uintT)cl * 16;
    uintT h4 = (uintT)h * 4;
    float aldh = ald[wid * 4 + h];
    float eh = lrelu(als[wid * 4 + h] + aldh);   // self logit (log2-scaled) = softmax shift
    int b = off[wid], e = off[wid + 1];
    f32x2 acc2[4] = {};
    float dsum = 0.f;
    int c = b + q;
    // pipeline prologue
    int v0n = 0, v1n = 0;
    if (c < e) v0n = csr[c];
    if (c + 4 < e) v1n = csr[c + 4];
    float al0n = *(const float*)(ab + (((uintT)v0n >> 4) + h4));
    float al1n = *(const float*)(ab + (((uintT)v1n >> 4) + h4));
    for (; c + 4 < e; c += 8) {
        int v0 = v0n, v1 = v1n;
        float al0 = al0n, al1 = al1n;
        uint4 hv0 = *(const uint4*)(xb + ((uintT)v0 + cl16));
        uint4 hv1 = *(const uint4*)(xb + ((uintT)v1 + cl16));
        if (c + 8 < e) v0n = csr[c + 8];
        if (c + 12 < e) v1n = csr[c + 12];
        al0n = *(const float*)(ab + (((uintT)v0n >> 4) + h4));
        al1n = *(const float*)(ab + (((uintT)v1n >> 4) + h4));
        float w0 = exp2f(lrelu(al0 + aldh) - eh);
        float w1 = exp2f(lrelu(al1 + aldh) - eh);
        dsum += w0 + w1;
        f32x2 w02 = {w0, w0};
        f32x2 w12 = {w1, w1};
        f32x2 p;
        p = (f32x2){bflo(hv0.x), bfhi(hv0.x)}; acc2[0] = __builtin_elementwise_fma(p, w02, acc2[0]);
        p = (f32x2){bflo(hv0.y), bfhi(hv0.y)}; acc2[1] = __builtin_elementwise_fma(p, w02, acc2[1]);
        p = (f32x2){bflo(hv0.z), bfhi(hv0.z)}; acc2[2] = __builtin_elementwise_fma(p, w02, acc2[2]);
        p = (f32x2){bflo(hv0.w), bfhi(hv0.w)}; acc2[3] = __builtin_elementwise_fma(p, w02, acc2[3]);
        p = (f32x2){bflo(hv1.x), bfhi(hv1.x)}; acc2[0] = __builtin_elementwise_fma(p, w12, acc2[0]);
        p = (f32x2){bflo(hv1.y), bfhi(hv1.y)}; acc2[1] = __builtin_elementwise_fma(p, w12, acc2[1]);
        p = (f32x2){bflo(hv1.z), bfhi(hv1.z)}; acc2[2] = __builtin_elementwise_fma(p, w12, acc2[2]);
        p = (f32x2){bflo(hv1.w), bfhi(hv1.w)}; acc2[3] = __builtin_elementwise_fma(p, w12, acc2[3]);
    }
    if (c < e) {
        uint4 hv = *(const uint4*)(xb + ((uintT)v0n + cl16));
        float w = exp2f(lrelu(al0n + aldh) - eh);
        dsum += w;
        f32x2 w2 = {w, w};
        f32x2 p;
        p = (f32x2){bflo(hv.x), bfhi(hv.x)}; acc2[0] = __builtin_elementwise_fma(p, w2, acc2[0]);
        p = (f32x2){bflo(hv.y), bfhi(hv.y)}; acc2[1] = __builtin_elementwise_fma(p, w2, acc2[1]);
        p = (f32x2){bflo(hv.z), bfhi(hv.z)}; acc2[2] = __builtin_elementwise_fma(p, w2, acc2[2]);
        p = (f32x2){bflo(hv.w), bfhi(hv.w)}; acc2[3] = __builtin_elementwise_fma(p, w2, acc2[3]);
    }
    float acc[8];
    #pragma unroll
    for (int i = 0; i < 4; ++i) {
        acc[2 * i] = acc2[i][0];
        acc[2 * i + 1] = acc2[i][1];
    }
    #pragma unroll
    for (int k = 0; k < 8; ++k) {
        acc[k] += __shfl_xor(acc[k], 16, 64);
        acc[k] += __shfl_xor(acc[k], 32, 64);
    }
    dsum += __shfl_xor(dsum, 16, 64);
    dsum += __shfl_xor(dsum, 32, 64);
    float inv = 1.f / (dsum + 1.f + 1e-16f);     // self weight = exp2(0) = 1
    uint4 sv = *(const uint4*)&xlh[(size_t)wid * HID + cl * 8];
    float sx[8];
    sx[0] = bflo(sv.x); sx[1] = bfhi(sv.x);
    sx[2] = bflo(sv.y); sx[3] = bfhi(sv.y);
    sx[4] = bflo(sv.z); sx[5] = bfhi(sv.z);
    sx[6] = bflo(sv.w); sx[7] = bfhi(sv.w);
    float4 bi0 = *(const float4*)&bias[cl * 8];
    float4 bi1 = *(const float4*)&bias[cl * 8 + 4];
    float o[8];
    #pragma unroll
    for (int k = 0; k < 8; ++k) {
        float bb = k < 4 ? (&bi0.x)[k] : (&bi1.x)[k - 4];
        o[k] = fmaf(acc[k] + sx[k], inv, bb);
    }
    float s1 = o[0] + o[1] + o[2] + o[3] + o[4] + o[5] + o[6] + o[7];
    #pragma unroll
    for (int m = 1; m < 16; m <<= 1) s1 += __shfl_xor(s1, m, 64);
    float mu = s1 * (1.0f / HID);
    float qv = 0.f;
    #pragma unroll
    for (int k = 0; k < 8; ++k) { float d = o[k] - mu; qv += d * d; }
    #pragma unroll
    for (int m = 1; m < 16; m <<= 1) qv += __shfl_xor(qv, m, 64);
    float rs = rsqrtf(qv * (1.0f / HID) + LN_EPS);
    if (q == 0) {
        float4 g0 = *(const float4*)&g[cl * 8];
        float4 g1 = *(const float4*)&g[cl * 8 + 4];
        float4 be0 = *(const float4*)&be[cl * 8];
        float4 be1 = *(const float4*)&be[cl * 8 + 4];
        uint4 rv = *(const uint4*)&resio[(size_t)wid * HID + cl * 8];
        float rr[8];
        rr[0] = bflo(rv.x); rr[1] = bfhi(rv.x);
        rr[2] = bflo(rv.y); rr[3] = bfhi(rv.y);
        rr[4] = bflo(rv.z); rr[5] = bfhi(rv.z);
        rr[6] = bflo(rv.w); rr[7] = bfhi(rv.w);
        float w[8];
        #pragma unroll
        for (int k = 0; k < 8; ++k) {
            float gg = k < 4 ? (&g0.x)[k] : (&g1.x)[k - 4];
            float ee = k < 4 ? (&be0.x)[k] : (&be1.x)[k - 4];
            w[k] = fmaxf((o[k] - mu) * rs * gg + ee, 0.f) + rr[k];
        }
        if (Wo) {
            float p0 = 0.f, p1 = 0.f;
            #pragma unroll
            for (int k = 0; k < 8; ++k) {
                int ch = cl * 8 + k;
                p0 = fmaf(w[k], Wo[ch * 2 + 0], p0);
                p1 = fmaf(w[k], Wo[ch * 2 + 1], p1);
            }
            #pragma unroll
            for (int m = 1; m < 16; m <<= 1) {
                p0 += __shfl_xor(p0, m, 64);
                p1 += __shfl_xor(p1, m, 64);
            }
            if (cl == 0) {
                float a_s = (p0 * aso[0] + p1 * aso[1]) * LOG2E;
                float a_d = (p0 * ado[0] + p1 * ado[1]) * LOG2E;
                xpack[wid] = make_float4(p0, p1, a_s, a_d);
            }
        } else {
            ushort4 hv0, hv1;
            hv0.x = f2bf(w[0]); hv0.y = f2bf(w[1]); hv0.z = f2bf(w[2]); hv0.w = f2bf(w[3]);
            hv1.x = f2bf(w[4]); hv1.y = f2bf(w[5]); hv1.z = f2bf(w[6]); hv1.w = f2bf(w[7]);
            *(ushort4*)&resio[(size_t)wid * HID + cl * 8] = hv0;
            *(ushort4*)&resio[(size_t)wid * HID + cl * 8 + 4] = hv1;
        }
    }
}

// ---------------- output aggregation: 16 lanes/node, 4 nodes/wave (csr = byte offsets) ----------------
__global__ __launch_bounds__(256) void out_agg(const float4* __restrict__ xpack, const int* __restrict__ off,
                                               const int* __restrict__ csr, const float* __restrict__ bo,
                                               float* __restrict__ out, int Nn) {
    int gid = blockIdx.x * 256 + threadIdx.x;
    int wid = gid >> 4;
    int l = threadIdx.x & 15;
    if (wid >= Nn) return;
    const char* pb = (const char*)xpack;
    float4 self = xpack[wid];
    float aldn = self.w;
    float eself = lrelu(self.z + aldn);
    int b = off[wid], e = off[wid + 1];
    float dl = 0.f, a0 = 0.f, a1 = 0.f;
    for (int j = b + l; j < e; j += 16) {
        float4 v = *(const float4*)(pb + ((uintT)csr[j] >> 4));
        float w = exp2f(lrelu(v.z + aldn) - eself);
        dl += w;
        a0 += w * v.x;
        a1 += w * v.y;
    }
    #pragma unroll
    for (int m = 1; m < 16; m <<= 1) {
        dl += __shfl_xor(dl, m, 64);
        a0 += __shfl_xor(a0, m, 64);
        a1 += __shfl_xor(a1, m, 64);
    }
    if (l == 0) {
        dl += 1.f;   // self weight exp2(0)
        a0 += self.x;
        a1 += self.y;
        float inv = 1.f / (dl + 1e-16f);
        out[wid * 2 + 0] = a0 * inv + bo[0];
        out[wid * 2 + 1] = a1 * inv + bo[1];
    }
}

extern "C" void kernel_launch(void* const* d_in, const int* in_sizes, int n_in,
                              void* d_out, int out_size, void* d_ws, size_t ws_size,
                              hipStream_t stream) {
    const float* x   = (const float*)d_in[0];
    const int*   ei  = (const int*)d_in[1];
    const float* W1  = (const float*)d_in[2];
    const float* as1 = (const float*)d_in[3];
    const float* ad1 = (const float*)d_in[4];
    const float* b1  = (const float*)d_in[5];
    const float* g1  = (const float*)d_in[6];
    const float* be1 = (const float*)d_in[7];
    const float* rw  = (const float*)d_in[8];
    const float* rb  = (const float*)d_in[9];
    const float* W2  = (const float*)d_in[10];
    const float* as2 = (const float*)d_in[11];
    const float* ad2 = (const float*)d_in[12];
    const float* b2  = (const float*)d_in[13];
    const float* g2  = (const float*)d_in[14];
    const float* be2 = (const float*)d_in[15];
    const float* W3  = (const float*)d_in[16];
    const float* as3 = (const float*)d_in[17];
    const float* ad3 = (const float*)d_in[18];
    const float* b3  = (const float*)d_in[19];
    const float* g3  = (const float*)d_in[20];
    const float* be3 = (const float*)d_in[21];
    const float* Wo  = (const float*)d_in[22];
    const float* aso = (const float*)d_in[23];
    const float* ado = (const float*)d_in[24];
    const float* bo  = (const float*)d_in[25];

    int N = in_sizes[0] / 64;   // 50000
    int E = in_sizes[1] / 2;    // 800000
    const int* srcE = ei;
    const int* dstE = ei + E;
    int NB = (N + 127) >> 7;    // 391 buckets

    char* w = (char*)d_ws;
    auto alloc = [&](size_t b) { char* p = w; w += (b + 255) & ~(size_t)255; return p; };
    int* off    = (int*)alloc((size_t)(N + 1) * 4);
    int* gcur   = (int*)alloc((size_t)NB * 4);
    int* csr    = (int*)alloc((size_t)E * 4);
    int2* bbuf  = (int2*)alloc((size_t)NB * BCAP * 8);
    ushortT* hresh = (ushortT*)alloc((size_t)N * HID * 2);
    ushortT* xlh = (ushortT*)alloc((size_t)N * HID * 2);
    ushortT* rwf = (ushortT*)alloc(8192 * 2);
    ushortT* W1f = (ushortT*)alloc(8192 * 2);
    ushortT* W2f = (ushortT*)alloc(16384 * 2);
    ushortT* W3f = (ushortT*)alloc(16384 * 2);
    float* als  = (float*)alloc((size_t)N * HEADS * 4);
    float* ald  = (float*)alloc((size_t)N * HEADS * 4);
    float4* xpack = (float4*)alloc((size_t)N * 16);

    // weight conversion (+ zeroes gcur for binA)
    wconv4_k<<<192, 256, 0, stream>>>(rw, W1, W2, W3, rwf, W1f, W2f, W3f, gcur, NB);
    binA_k<<<(E + 4095) / 4096, 256, 0, stream>>>(srcE, dstE, gcur, bbuf, E, NB);
    binB_k<<<NB, 256, 0, stream>>>(bbuf, gcur, off, csr, N, E);

    int gG = (N + 63) / 64;   // MFMA gemm grid
    int gW = (N + 3) / 4;     // wave-per-node grid
    int gO = (N * 16 + 255) / 256;   // 16 lanes/node grid

    // ---- layer 1 (fused residual + W1 projection, MFMA, inline x->bf16) ----
    gemm_mfma_x<<<gG, 256, 0, stream>>>(x, rwf, W1f, rb, as1, ad1, hresh, xlh, als, ald, N);
    gat_fused<<<gW, 256, 0, stream>>>(xlh, als, ald, off, csr, b1, g1, be1, hresh,
                                      nullptr, nullptr, nullptr, nullptr, N);

    // ---- layer 2 ----
    gemm_mfma_h<<<gG, 256, 0, stream>>>(hresh, W2f, as2, ad2, xlh, als, ald, N);
    gat_fused<<<gW, 256, 0, stream>>>(xlh, als, ald, off, csr, b2, g2, be2, hresh,
                                      nullptr, nullptr, nullptr, nullptr, N);

    // ---- layer 3 (fused output projection) ----
    gemm_mfma_h<<<gG, 256, 0, stream>>>(hresh, W3f, as3, ad3, xlh, als, ald, N);
    gat_fused<<<gW, 256, 0, stream>>>(xlh, als, ald, off, csr, b3, g3, be3, hresh,
                                      Wo, aso, ado, xpack, N);

    // ---- output aggregation ----
    out_agg<<<gO, 256, 0, stream>>>(xpack, off, csr, bo, (float*)d_out, N);
}

// Round 16
// 211.519 us; speedup vs baseline: 1.0020x; 1.0015x over previous
//
#include <hip/hip_runtime.h>
#include <math.h>

#define HID 128
#define HEADS 4
#define NEG_SLOPE 0.2f
#define LN_EPS 1e-5f
#define LOG2E 1.44269504088896f
#define BCAP 4096   // per-bucket capacity (avg 2046 for N=50K, E=800K)

typedef unsigned short ushortT;
typedef unsigned int uintT;
typedef __attribute__((ext_vector_type(8))) short bf16x8;
typedef __attribute__((ext_vector_type(4))) float f32x4;
typedef __attribute__((ext_vector_type(2))) float f32x2;

__device__ __forceinline__ float lrelu(float v) { return v > 0.f ? v : NEG_SLOPE * v; }
__device__ __forceinline__ float bflo(uintT v) { return __uint_as_float(v << 16); }
__device__ __forceinline__ float bfhi(uintT v) { return __uint_as_float(v & 0xffff0000u); }

__device__ __forceinline__ ushortT f2bf(float f) {
    uintT u = __float_as_uint(f);
    u += 0x7fffu + ((u >> 16) & 1u);   // round-to-nearest-even
    return (ushortT)(u >> 16);
}

// ---------------- edge binning (pass A): bin edges by dst>>7; gcur ends as per-bucket counts ----------------
__global__ __launch_bounds__(256) void binA_k(const int* __restrict__ src, const int* __restrict__ dst,
                                              int* __restrict__ gcur, int2* __restrict__ buf, int E, int NB) {
    __shared__ int hist[512];
    __shared__ int bbase[512];
    __shared__ int lcur[512];
    int t = threadIdx.x;
    for (int i = t; i < NB; i += 256) { hist[i] = 0; lcur[i] = 0; }
    __syncthreads();
    int e0 = blockIdx.x * 4096;
    int2 ed[16];
    #pragma unroll
    for (int j = 0; j < 16; ++j) {
        int idx = e0 + j * 256 + t;
        if (idx < E) {
            ed[j].x = src[idx];
            ed[j].y = dst[idx];
            atomicAdd(&hist[ed[j].y >> 7], 1);
        } else {
            ed[j].y = -1;
        }
    }
    __syncthreads();
    for (int i = t; i < NB; i += 256) {
        int c = hist[i];
        bbase[i] = c > 0 ? atomicAdd(&gcur[i], c) : 0;
    }
    __syncthreads();
    #pragma unroll
    for (int j = 0; j < 16; ++j) {
        if (ed[j].y >= 0) {
            int b = ed[j].y >> 7;
            int pos = bbase[b] + atomicAdd(&lcur[b], 1);
            buf[(size_t)b * BCAP + pos] = ed[j];
        }
    }
}

// ---------------- pass B: compute own bucket base, per-node count+scan -> off, scatter csr (BYTE offsets: src*256) ----------------
__global__ __launch_bounds__(256) void binB_k(const int2* __restrict__ buf, const int* __restrict__ bcnt,
                                              int* __restrict__ off, int* __restrict__ csr, int Nn, int E) {
    __shared__ int cnt[128];
    __shared__ int pre[128];
    __shared__ int cur[128];
    __shared__ int sbase;
    int t = threadIdx.x, b = blockIdx.x;
    if (t == 0) sbase = 0;
    if (t < 128) cnt[t] = 0;
    __syncthreads();
    int bacc = 0;
    for (int i = t; i < b; i += 256) bacc += bcnt[i];
    #pragma unroll
    for (int m = 1; m < 64; m <<= 1) bacc += __shfl_xor(bacc, m, 64);
    if ((t & 63) == 0 && bacc != 0) atomicAdd(&sbase, bacc);
    int nb = bcnt[b];
    int nodebase = b << 7;
    for (int i = t; i < nb; i += 256)
        atomicAdd(&cnt[buf[(size_t)b * BCAP + i].y - nodebase], 1);
    __syncthreads();
    if (t < 128) pre[t] = cnt[t];
    __syncthreads();
    #pragma unroll
    for (int ofs = 1; ofs < 128; ofs <<= 1) {
        int v = 0;
        if (t < 128 && t >= ofs) v = pre[t - ofs];
        __syncthreads();
        if (t < 128) pre[t] += v;
        __syncthreads();
    }
    if (t < 128) {
        int node = nodebase + t;
        int o = sbase + pre[t] - cnt[t];
        if (node < Nn) off[node] = o;
        cur[t] = o;
    }
    if (b == 0 && t == 0) off[Nn] = E;
    __syncthreads();
    for (int i = t; i < nb; i += 256) {
        int2 e = buf[(size_t)b * BCAP + i];
        int p = atomicAdd(&cur[e.y - nodebase], 1);
        csr[p] = e.x << 8;     // byte offset into 256B-per-node tables
    }
}

// ---------------- weight conversion into MFMA B-fragment layout (+ zero gcur) ----------------
__global__ __launch_bounds__(256) void wconv4_k(const float* __restrict__ rw, const float* __restrict__ W1,
                                                const float* __restrict__ W2, const float* __restrict__ W3,
                                                ushortT* __restrict__ rwf, ushortT* __restrict__ W1f,
                                                ushortT* __restrict__ W2f, ushortT* __restrict__ W3f,
                                                int* __restrict__ gcur, int NB) {
    int id = blockIdx.x * 256 + threadIdx.x;
    if (id < NB) gcur[id] = 0;
    const float* Wsrc; ushortT* Wdst; int kdiv; int lid;
    if (id < 8192)        { Wsrc = rw; Wdst = rwf; kdiv = 2; lid = id; }
    else if (id < 16384)  { Wsrc = W1; Wdst = W1f; kdiv = 2; lid = id - 8192; }
    else if (id < 32768)  { Wsrc = W2; Wdst = W2f; kdiv = 4; lid = id - 16384; }
    else if (id < 49152)  { Wsrc = W3; Wdst = W3f; kdiv = 4; lid = id - 32768; }
    else return;
    int i = lid & 7;
    int lane = (lid >> 3) & 63;
    int rest = lid >> 9;            // j*kdiv + ks
    int ks = rest % kdiv;
    int j = rest / kdiv;
    int k = ks * 32 + (lane >> 4) * 8 + i;
    int n = j * 16 + (lane & 15);
    Wdst[lid] = f2bf(Wsrc[k * HID + n]);
}

// ---------------- MFMA GEMM (x layer, K=64): inline fp32->bf16 A, bf16 residual + xl + attn dots (x log2e) ----------------
__global__ __launch_bounds__(256) void gemm_mfma_x(
        const float* __restrict__ X, const ushortT* __restrict__ rwf, const ushortT* __restrict__ W1f,
        const float* __restrict__ rb, const float* __restrict__ a_srcp, const float* __restrict__ a_dstp,
        ushortT* __restrict__ Resh, ushortT* __restrict__ Ch,
        float* __restrict__ als, float* __restrict__ ald, int M) {
    int t = threadIdx.x;
    int wave = t >> 6, lane = t & 63;
    int row0 = blockIdx.x * 64 + wave * 16;
    int cl = lane & 15, grp = lane >> 4;
    int rA = row0 + cl;
    f32x4 accR[8] = {};
    f32x4 acc1[8] = {};
    #pragma unroll
    for (int ks = 0; ks < 2; ++ks) {
        bf16x8 afr = {};
        if (rA < M) {
            const float* xr = &X[(size_t)rA * 64 + ks * 32 + grp * 8];
            float4 a0 = *(const float4*)xr;
            float4 a1 = *(const float4*)(xr + 4);
            afr[0] = (short)f2bf(a0.x); afr[1] = (short)f2bf(a0.y);
            afr[2] = (short)f2bf(a0.z); afr[3] = (short)f2bf(a0.w);
            afr[4] = (short)f2bf(a1.x); afr[5] = (short)f2bf(a1.y);
            afr[6] = (short)f2bf(a1.z); afr[7] = (short)f2bf(a1.w);
        }
        #pragma unroll
        for (int j = 0; j < 8; ++j) {
            bf16x8 br = *(const bf16x8*)&rwf[(((size_t)j * 2 + ks) * 64 + lane) * 8];
            accR[j] = __builtin_amdgcn_mfma_f32_16x16x32_bf16(afr, br, accR[j], 0, 0, 0);
            bf16x8 b1 = *(const bf16x8*)&W1f[(((size_t)j * 2 + ks) * 64 + lane) * 8];
            acc1[j] = __builtin_amdgcn_mfma_f32_16x16x32_bf16(afr, b1, acc1[j], 0, 0, 0);
        }
    }
    float asv[8], adv[8], rbv[8];
    #pragma unroll
    for (int j = 0; j < 8; ++j) {
        asv[j] = a_srcp[j * 16 + cl] * LOG2E;
        adv[j] = a_dstp[j * 16 + cl] * LOG2E;
        rbv[j] = rb[j * 16 + cl];
    }
    #pragma unroll
    for (int reg = 0; reg < 4; ++reg) {
        int r = row0 + grp * 4 + reg;
        bool ok = r < M;
        if (ok) {
            #pragma unroll
            for (int j = 0; j < 8; ++j) {
                Resh[(size_t)r * HID + j * 16 + cl] = f2bf(accR[j][reg] + rbv[j]);
                Ch[(size_t)r * HID + j * 16 + cl] = f2bf(acc1[j][reg]);
            }
        }
        float ps[4], pd[4];
        #pragma unroll
        for (int h = 0; h < 4; ++h) {
            ps[h] = acc1[2 * h][reg] * asv[2 * h] + acc1[2 * h + 1][reg] * asv[2 * h + 1];
            pd[h] = acc1[2 * h][reg] * adv[2 * h] + acc1[2 * h + 1][reg] * adv[2 * h + 1];
        }
        #pragma unroll
        for (int m = 1; m < 16; m <<= 1) {
            #pragma unroll
            for (int h = 0; h < 4; ++h) {
                ps[h] += __shfl_xor(ps[h], m, 64);
                pd[h] += __shfl_xor(pd[h], m, 64);
            }
        }
        if (cl == 0 && ok) {
            *(float4*)&als[(size_t)r * 4] = make_float4(ps[0], ps[1], ps[2], ps[3]);
            *(float4*)&ald[(size_t)r * 4] = make_float4(pd[0], pd[1], pd[2], pd[3]);
        }
    }
}

// ---------------- MFMA GEMM (hidden layers, K=128): Ch + attn dots (x log2e) ----------------
__global__ __launch_bounds__(256) void gemm_mfma_h(
        const ushortT* __restrict__ Ah, const ushortT* __restrict__ Wf,
        const float* __restrict__ a_srcp, const float* __restrict__ a_dstp,
        ushortT* __restrict__ Ch, float* __restrict__ als, float* __restrict__ ald, int M) {
    int t = threadIdx.x;
    int wave = t >> 6, lane = t & 63;
    int row0 = blockIdx.x * 64 + wave * 16;
    int cl = lane & 15, grp = lane >> 4;
    int rA = row0 + cl;
    f32x4 acc[8] = {};
    #pragma unroll
    for (int ks = 0; ks < 4; ++ks) {
        bf16x8 afr = {};
        if (rA < M) afr = *(const bf16x8*)&Ah[(size_t)rA * HID + ks * 32 + grp * 8];
        #pragma unroll
        for (int j = 0; j < 8; ++j) {
            bf16x8 br = *(const bf16x8*)&Wf[(((size_t)j * 4 + ks) * 64 + lane) * 8];
            acc[j] = __builtin_amdgcn_mfma_f32_16x16x32_bf16(afr, br, acc[j], 0, 0, 0);
        }
    }
    float asv[8], adv[8];
    #pragma unroll
    for (int j = 0; j < 8; ++j) {
        asv[j] = a_srcp[j * 16 + cl] * LOG2E;
        adv[j] = a_dstp[j * 16 + cl] * LOG2E;
    }
    #pragma unroll
    for (int reg = 0; reg < 4; ++reg) {
        int r = row0 + grp * 4 + reg;
        bool ok = r < M;
        if (ok) {
            #pragma unroll
            for (int j = 0; j < 8; ++j)
                Ch[(size_t)r * HID + j * 16 + cl] = f2bf(acc[j][reg]);
        }
        float ps[4], pd[4];
        #pragma unroll
        for (int h = 0; h < 4; ++h) {
            ps[h] = acc[2 * h][reg] * asv[2 * h] + acc[2 * h + 1][reg] * asv[2 * h + 1];
            pd[h] = acc[2 * h][reg] * adv[2 * h] + acc[2 * h + 1][reg] * adv[2 * h + 1];
        }
        #pragma unroll
        for (int m = 1; m < 16; m <<= 1) {
            #pragma unroll
            for (int h = 0; h < 4; ++h) {
                ps[h] += __shfl_xor(ps[h], m, 64);
                pd[h] += __shfl_xor(pd[h], m, 64);
            }
        }
        if (cl == 0 && ok) {
            *(float4*)&als[(size_t)r * 4] = make_float4(ps[0], ps[1], ps[2], ps[3]);
            *(float4*)&ald[(size_t)r * 4] = make_float4(pd[0], pd[1], pd[2], pd[3]);
        }
    }
}

// ---------------- fully fused GAT: single-pass online softmax (exp2) + LN + ReLU + bf16 residual ----------------
// Full modulo-scheduled pipeline: csr/als AND xlh row loads for iteration i+1 issued during iteration i.
__global__ __launch_bounds__(256) void gat_fused(
        const ushortT* __restrict__ xlh, const float* __restrict__ als,
        const float* __restrict__ ald, const int* __restrict__ off,
        const int* __restrict__ csr, const float* __restrict__ bias,
        const float* __restrict__ g, const float* __restrict__ be,
        ushortT* __restrict__ resio,
        const float* __restrict__ Wo, const float* __restrict__ aso, const float* __restrict__ ado,
        float4* __restrict__ xpack, int Nn) {
    int gid = blockIdx.x * 256 + threadIdx.x;
    int wid = gid >> 6, lane = threadIdx.x & 63;
    if (wid >= Nn) return;
    int q = lane >> 4;
    int cl = lane & 15;
    int h = cl >> 2;
    const char* xb = (const char*)xlh;
    const char* ab = (const char*)als;
    uintT cl16 = (uintT)cl * 16;
    uintT h4 = (uintT)h * 4;
    float aldh = ald[wid * 4 + h];
    float eh = lrelu(als[wid * 4 + h] + aldh);   // self logit (log2-scaled) = softmax shift
    int b = off[wid], e = off[wid + 1];
    f32x2 acc2[4] = {};
    float dsum = 0.f;
    int c = b + q;
    // pipeline prologue: indices, attrs, and rows for the first pair
    int v0 = 0, v1 = 0;
    if (c < e) v0 = csr[c];
    if (c + 4 < e) v1 = csr[c + 4];
    float al0 = *(const float*)(ab + (((uintT)v0 >> 4) + h4));
    float al1 = *(const float*)(ab + (((uintT)v1 >> 4) + h4));
    uint4 hv0 = *(const uint4*)(xb + ((uintT)v0 + cl16));
    uint4 hv1 = *(const uint4*)(xb + ((uintT)v1 + cl16));
    for (; c + 4 < e; c += 8) {
        // issue next pair's loads first (rows consumed next iteration)
        int nv0 = v0, nv1 = v1;
        if (c + 8 < e) nv0 = csr[c + 8];
        if (c + 12 < e) nv1 = csr[c + 12];
        float nal0 = *(const float*)(ab + (((uintT)nv0 >> 4) + h4));
        float nal1 = *(const float*)(ab + (((uintT)nv1 >> 4) + h4));
        uint4 nhv0 = *(const uint4*)(xb + ((uintT)nv0 + cl16));
        uint4 nhv1 = *(const uint4*)(xb + ((uintT)nv1 + cl16));
        // compute with current pair (rows already in flight since last iteration)
        float w0 = exp2f(lrelu(al0 + aldh) - eh);
        float w1 = exp2f(lrelu(al1 + aldh) - eh);
        dsum += w0 + w1;
        f32x2 w02 = {w0, w0};
        f32x2 w12 = {w1, w1};
        f32x2 p;
        p = (f32x2){bflo(hv0.x), bfhi(hv0.x)}; acc2[0] = __builtin_elementwise_fma(p, w02, acc2[0]);
        p = (f32x2){bflo(hv0.y), bfhi(hv0.y)}; acc2[1] = __builtin_elementwise_fma(p, w02, acc2[1]);
        p = (f32x2){bflo(hv0.z), bfhi(hv0.z)}; acc2[2] = __builtin_elementwise_fma(p, w02, acc2[2]);
        p = (f32x2){bflo(hv0.w), bfhi(hv0.w)}; acc2[3] = __builtin_elementwise_fma(p, w02, acc2[3]);
        p = (f32x2){bflo(hv1.x), bfhi(hv1.x)}; acc2[0] = __builtin_elementwise_fma(p, w12, acc2[0]);
        p = (f32x2){bflo(hv1.y), bfhi(hv1.y)}; acc2[1] = __builtin_elementwise_fma(p, w12, acc2[1]);
        p = (f32x2){bflo(hv1.z), bfhi(hv1.z)}; acc2[2] = __builtin_elementwise_fma(p, w12, acc2[2]);
        p = (f32x2){bflo(hv1.w), bfhi(hv1.w)}; acc2[3] = __builtin_elementwise_fma(p, w12, acc2[3]);
        // rotate
        v0 = nv0; v1 = nv1; al0 = nal0; al1 = nal1; hv0 = nhv0; hv1 = nhv1;
    }
    if (c < e) {
        // pipeline invariant: hv0/al0 hold edge c's row and attr
        float w = exp2f(lrelu(al0 + aldh) - eh);
        dsum += w;
        f32x2 w2 = {w, w};
        f32x2 p;
        p = (f32x2){bflo(hv0.x), bfhi(hv0.x)}; acc2[0] = __builtin_elementwise_fma(p, w2, acc2[0]);
        p = (f32x2){bflo(hv0.y), bfhi(hv0.y)}; acc2[1] = __builtin_elementwise_fma(p, w2, acc2[1]);
        p = (f32x2){bflo(hv0.z), bfhi(hv0.z)}; acc2[2] = __builtin_elementwise_fma(p, w2, acc2[2]);
        p = (f32x2){bflo(hv0.w), bfhi(hv0.w)}; acc2[3] = __builtin_elementwise_fma(p, w2, acc2[3]);
    }
    float acc[8];
    #pragma unroll
    for (int i = 0; i < 4; ++i) {
        acc[2 * i] = acc2[i][0];
        acc[2 * i + 1] = acc2[i][1];
    }
    #pragma unroll
    for (int k = 0; k < 8; ++k) {
        acc[k] += __shfl_xor(acc[k], 16, 64);
        acc[k] += __shfl_xor(acc[k], 32, 64);
    }
    dsum += __shfl_xor(dsum, 16, 64);
    dsum += __shfl_xor(dsum, 32, 64);
    float inv = 1.f / (dsum + 1.f + 1e-16f);     // self weight = exp2(0) = 1
    uint4 sv = *(const uint4*)&xlh[(size_t)wid * HID + cl * 8];
    float sx[8];
    sx[0] = bflo(sv.x); sx[1] = bfhi(sv.x);
    sx[2] = bflo(sv.y); sx[3] = bfhi(sv.y);
    sx[4] = bflo(sv.z); sx[5] = bfhi(sv.z);
    sx[6] = bflo(sv.w); sx[7] = bfhi(sv.w);
    float4 bi0 = *(const float4*)&bias[cl * 8];
    float4 bi1 = *(const float4*)&bias[cl * 8 + 4];
    float o[8];
    #pragma unroll
    for (int k = 0; k < 8; ++k) {
        float bb = k < 4 ? (&bi0.x)[k] : (&bi1.x)[k - 4];
        o[k] = fmaf(acc[k] + sx[k], inv, bb);
    }
    float s1 = o[0] + o[1] + o[2] + o[3] + o[4] + o[5] + o[6] + o[7];
    #pragma unroll
    for (int m = 1; m < 16; m <<= 1) s1 += __shfl_xor(s1, m, 64);
    float mu = s1 * (1.0f / HID);
    float qv = 0.f;
    #pragma unroll
    for (int k = 0; k < 8; ++k) { float d = o[k] - mu; qv += d * d; }
    #pragma unroll
    for (int m = 1; m < 16; m <<= 1) qv += __shfl_xor(qv, m, 64);
    float rs = rsqrtf(qv * (1.0f / HID) + LN_EPS);
    if (q == 0) {
        float4 g0 = *(const float4*)&g[cl * 8];
        float4 g1 = *(const float4*)&g[cl * 8 + 4];
        float4 be0 = *(const float4*)&be[cl * 8];
        float4 be1 = *(const float4*)&be[cl * 8 + 4];
        uint4 rv = *(const uint4*)&resio[(size_t)wid * HID + cl * 8];
        float rr[8];
        rr[0] = bflo(rv.x); rr[1] = bfhi(rv.x);
        rr[2] = bflo(rv.y); rr[3] = bfhi(rv.y);
        rr[4] = bflo(rv.z); rr[5] = bfhi(rv.z);
        rr[6] = bflo(rv.w); rr[7] = bfhi(rv.w);
        float w[8];
        #pragma unroll
        for (int k = 0; k < 8; ++k) {
            float gg = k < 4 ? (&g0.x)[k] : (&g1.x)[k - 4];
            float ee = k < 4 ? (&be0.x)[k] : (&be1.x)[k - 4];
            w[k] = fmaxf((o[k] - mu) * rs * gg + ee, 0.f) + rr[k];
        }
        if (Wo) {
            float p0 = 0.f, p1 = 0.f;
            #pragma unroll
            for (int k = 0; k < 8; ++k) {
                int ch = cl * 8 + k;
                p0 = fmaf(w[k], Wo[ch * 2 + 0], p0);
                p1 = fmaf(w[k], Wo[ch * 2 + 1], p1);
            }
            #pragma unroll
            for (int m = 1; m < 16; m <<= 1) {
                p0 += __shfl_xor(p0, m, 64);
                p1 += __shfl_xor(p1, m, 64);
            }
            if (cl == 0) {
                float a_s = (p0 * aso[0] + p1 * aso[1]) * LOG2E;
                float a_d = (p0 * ado[0] + p1 * ado[1]) * LOG2E;
                xpack[wid] = make_float4(p0, p1, a_s, a_d);
            }
        } else {
            ushort4 hw0, hw1;
            hw0.x = f2bf(w[0]); hw0.y = f2bf(w[1]); hw0.z = f2bf(w[2]); hw0.w = f2bf(w[3]);
            hw1.x = f2bf(w[4]); hw1.y = f2bf(w[5]); hw1.z = f2bf(w[6]); hw1.w = f2bf(w[7]);
            *(ushort4*)&resio[(size_t)wid * HID + cl * 8] = hw0;
            *(ushort4*)&resio[(size_t)wid * HID + cl * 8 + 4] = hw1;
        }
    }
}

// ---------------- output aggregation: 16 lanes/node, 4 nodes/wave (csr = byte offsets) ----------------
__global__ __launch_bounds__(256) void out_agg(const float4* __restrict__ xpack, const int* __restrict__ off,
                                               const int* __restrict__ csr, const float* __restrict__ bo,
                                               float* __restrict__ out, int Nn) {
    int gid = blockIdx.x * 256 + threadIdx.x;
    int wid = gid >> 4;
    int l = threadIdx.x & 15;
    if (wid >= Nn) return;
    const char* pb = (const char*)xpack;
    float4 self = xpack[wid];
    float aldn = self.w;
    float eself = lrelu(self.z + aldn);
    int b = off[wid], e = off[wid + 1];
    float dl = 0.f, a0 = 0.f, a1 = 0.f;
    for (int j = b + l; j < e; j += 16) {
        float4 v = *(const float4*)(pb + ((uintT)csr[j] >> 4));
        float w = exp2f(lrelu(v.z + aldn) - eself);
        dl += w;
        a0 += w * v.x;
        a1 += w * v.y;
    }
    #pragma unroll
    for (int m = 1; m < 16; m <<= 1) {
        dl += __shfl_xor(dl, m, 64);
        a0 += __shfl_xor(a0, m, 64);
        a1 += __shfl_xor(a1, m, 64);
    }
    if (l == 0) {
        dl += 1.f;   // self weight exp2(0)
        a0 += self.x;
        a1 += self.y;
        float inv = 1.f / (dl + 1e-16f);
        out[wid * 2 + 0] = a0 * inv + bo[0];
        out[wid * 2 + 1] = a1 * inv + bo[1];
    }
}

extern "C" void kernel_launch(void* const* d_in, const int* in_sizes, int n_in,
                              void* d_out, int out_size, void* d_ws, size_t ws_size,
                              hipStream_t stream) {
    const float* x   = (const float*)d_in[0];
    const int*   ei  = (const int*)d_in[1];
    const float* W1  = (const float*)d_in[2];
    const float* as1 = (const float*)d_in[3];
    const float* ad1 = (const float*)d_in[4];
    const float* b1  = (const float*)d_in[5];
    const float* g1  = (const float*)d_in[6];
    const float* be1 = (const float*)d_in[7];
    const float* rw  = (const float*)d_in[8];
    const float* rb  = (const float*)d_in[9];
    const float* W2  = (const float*)d_in[10];
    const float* as2 = (const float*)d_in[11];
    const float* ad2 = (const float*)d_in[12];
    const float* b2  = (const float*)d_in[13];
    const float* g2  = (const float*)d_in[14];
    const float* be2 = (const float*)d_in[15];
    const float* W3  = (const float*)d_in[16];
    const float* as3 = (const float*)d_in[17];
    const float* ad3 = (const float*)d_in[18];
    const float* b3  = (const float*)d_in[19];
    const float* g3  = (const float*)d_in[20];
    const float* be3 = (const float*)d_in[21];
    const float* Wo  = (const float*)d_in[22];
    const float* aso = (const float*)d_in[23];
    const float* ado = (const float*)d_in[24];
    const float* bo  = (const float*)d_in[25];

    int N = in_sizes[0] / 64;   // 50000
    int E = in_sizes[1] / 2;    // 800000
    const int* srcE = ei;
    const int* dstE = ei + E;
    int NB = (N + 127) >> 7;    // 391 buckets

    char* w = (char*)d_ws;
    auto alloc = [&](size_t b) { char* p = w; w += (b + 255) & ~(size_t)255; return p; };
    int* off    = (int*)alloc((size_t)(N + 1) * 4);
    int* gcur   = (int*)alloc((size_t)NB * 4);
    int* csr    = (int*)alloc((size_t)E * 4);
    int2* bbuf  = (int2*)alloc((size_t)NB * BCAP * 8);
    ushortT* hresh = (ushortT*)alloc((size_t)N * HID * 2);
    ushortT* xlh = (ushortT*)alloc((size_t)N * HID * 2);
    ushortT* rwf = (ushortT*)alloc(8192 * 2);
    ushortT* W1f = (ushortT*)alloc(8192 * 2);
    ushortT* W2f = (ushortT*)alloc(16384 * 2);
    ushortT* W3f = (ushortT*)alloc(16384 * 2);
    float* als  = (float*)alloc((size_t)N * HEADS * 4);
    float* ald  = (float*)alloc((size_t)N * HEADS * 4);
    float4* xpack = (float4*)alloc((size_t)N * 16);

    // weight conversion (+ zeroes gcur for binA)
    wconv4_k<<<192, 256, 0, stream>>>(rw, W1, W2, W3, rwf, W1f, W2f, W3f, gcur, NB);
    binA_k<<<(E + 4095) / 4096, 256, 0, stream>>>(srcE, dstE, gcur, bbuf, E, NB);
    binB_k<<<NB, 256, 0, stream>>>(bbuf, gcur, off, csr, N, E);

    int gG = (N + 63) / 64;   // MFMA gemm grid
    int gW = (N + 3) / 4;     // wave-per-node grid
    int gO = (N * 16 + 255) / 256;   // 16 lanes/node grid

    // ---- layer 1 (fused residual + W1 projection, MFMA, inline x->bf16) ----
    gemm_mfma_x<<<gG, 256, 0, stream>>>(x, rwf, W1f, rb, as1, ad1, hresh, xlh, als, ald, N);
    gat_fused<<<gW, 256, 0, stream>>>(xlh, als, ald, off, csr, b1, g1, be1, hresh,
                                      nullptr, nullptr, nullptr, nullptr, N);

    // ---- layer 2 ----
    gemm_mfma_h<<<gG, 256, 0, stream>>>(hresh, W2f, as2, ad2, xlh, als, ald, N);
    gat_fused<<<gW, 256, 0, stream>>>(xlh, als, ald, off, csr, b2, g2, be2, hresh,
                                      nullptr, nullptr, nullptr, nullptr, N);

    // ---- layer 3 (fused output projection) ----
    gemm_mfma_h<<<gG, 256, 0, stream>>>(hresh, W3f, as3, ad3, xlh, als, ald, N);
    gat_fused<<<gW, 256, 0, stream>>>(xlh, als, ald, off, csr, b3, g3, be3, hresh,
                                      Wo, aso, ado, xpack, N);

    // ---- output aggregation ----
    out_agg<<<gO, 256, 0, stream>>>(xpack, off, csr, bo, (float*)d_out, N);
}